// Round 6
// baseline (267.803 us; speedup 1.0000x reference)
//
#include <hip/hip_runtime.h>
#include <stdint.h>
#include <math.h>

#define HW_ 16384   // H*W = 128*128
#define C_  256
#define NT  8       // tiles per block (each tile = 64 positions)
#define ROWB 1040   // LDS bytes per position-row: 1024 data + 16 pad

typedef short bf16x8 __attribute__((ext_vector_type(8)));
typedef float f32x4  __attribute__((ext_vector_type(4)));
typedef unsigned int u32;

__device__ __forceinline__ unsigned short f2bf(float f) {
  union { float f; unsigned u; } v; v.f = f;
  unsigned u = v.u;
  u += 0x7fffu + ((u >> 16) & 1u);   // RNE
  return (unsigned short)(u >> 16);
}

// barrier WITHOUT vmcnt drain: LDS ordering only; prefetch loads stay in flight
#define BARRIER_LGKM() asm volatile("s_waitcnt lgkmcnt(0)\n\ts_barrier" ::: "memory")

// -------- kernel 0: prep (W -> bf16 in MFMA-fragment order, BN consts) ------
// Wp layout: idx = ks*8192 + kg*2048 + mf*128 + r*8 + e  (shorts)
__global__ __launch_bounds__(256) void k0_prep(
    const float* __restrict__ w_fe, const float* __restrict__ gamma,
    const float* __restrict__ beta, const float* __restrict__ mean,
    const float* __restrict__ var, unsigned short* __restrict__ Wp,
    float* __restrict__ scale, float* __restrict__ shift)
{
  int i = blockIdx.x * 256 + threadIdx.x;
  if (i < 131072) {
    int e  = i & 7;
    int r  = (i >> 3) & 15;
    int mf = (i >> 7) & 15;
    int kg = (i >> 11) & 3;
    int ks = i >> 13;
    int row = mf * 16 + r;              // output channel
    int k   = ks * 32 + kg * 8 + e;     // input channel (0..511)
    Wp[i] = f2bf(w_fe[row * 512 + k]);
  }
  if (i < 256) {
    float sc = gamma[i] * rsqrtf(var[i] + 1e-5f);
    scale[i] = sc;
    shift[i] = beta[i] - mean[i] * sc;
  }
}

// ------- kernel 1: persistent-W bf16 MFMA GEMM + BN + ReLU + pool -------
// 16 waves; wave w = m-frag w. A-frags in registers/AGPRs for the whole
// kernel. X tile [64 pos][512 k] bf16 in LDS (+16B row pad), double-buffered.
// 2-tile-deep register prefetch; raw barrier (no vmcnt drain) per tile.
__global__ __launch_bounds__(1024, 4) void k1_gemm_pool(
    const float* __restrict__ x1, const float* __restrict__ x2,
    const unsigned short* __restrict__ Wp,
    const float* __restrict__ scale, const float* __restrict__ shift,
    float* __restrict__ pool_part)
{
  __shared__ __align__(16) char Bl[2][64 * ROWB];   // 2 x 66560 B

  const int tid  = threadIdx.x;
  const int wave = tid >> 6;        // = mf
  const int lane = tid & 63;
  const int r15  = lane & 15;
  const int kg   = lane >> 4;
  const int blk  = blockIdx.x;
  const int b    = blk >> 5;                 // batch
  const int tile0 = (blk & 31) * NT;

  const float* xb1 = x1 + (size_t)b * C_ * HW_;
  const float* xb2 = x2 + (size_t)b * C_ * HW_;

  // staging decomposition: v -> k-pair fine index, u -> pos fine index
  const int v  = tid & 7;
  const int u2 = ((tid >> 3) & 7) * 2;
  const int kp = wave * 8 + v;        // k-pair 0..127 within a half
  const int kb = kp * 4;              // byte offset of (2kp) within row data

  const int kg16 = kg * 16;

  // ---- A-frags once for this wave ----
  bf16x8 Af[16];
#pragma unroll
  for (int ks = 0; ks < 16; ++ks)
    Af[ks] = *(const bf16x8*)(Wp + ks * 8192 + kg * 2048 + wave * 128 + r15 * 8);

  const int chbase = wave * 16 + kg * 4;
  const float4 sc4 = *(const float4*)&scale[chbase];
  const float4 sh4 = *(const float4*)&shift[chbase];

  float pool0 = 0.f, pool1 = 0.f, pool2 = 0.f, pool3 = 0.f;

  // two prefetch register banks; chunk CH: H = CH>>1 (input half), Q0 = (CH&1)*2
  float2 gA0[4][2], gB0[4][2];   // bank 0
  float2 gA1[4][2], gB1[4][2];   // bank 1

// Load chunk CH of tile at base position P0 into bank (GA,GB). CH literal.
#define ISSUE_CH(GA, GB, CH, P0)                                              \
  {                                                                           \
    const float* xsrc = (((CH) >> 1) == 0 ? xb1 : xb2)                        \
                        + (size_t)(kp * 2) * HW_ + (P0) + ((CH)&1) * 32 + u2; \
    GA[CH][0] = *(const float2*)(xsrc);                                       \
    GB[CH][0] = *(const float2*)(xsrc + HW_);                                 \
    GA[CH][1] = *(const float2*)(xsrc + 16);                                  \
    GB[CH][1] = *(const float2*)(xsrc + HW_ + 16);                            \
  }

#define ISSUE_T(GA, GB, P0)                                                   \
  { ISSUE_CH(GA, GB, 0, P0) ISSUE_CH(GA, GB, 1, P0)                           \
    ISSUE_CH(GA, GB, 2, P0) ISSUE_CH(GA, GB, 3, P0) }

// Write chunk CH of a bank into LDS buffer BUF (4 x ds_write_b32).
#define WRITE_CH(GA, GB, CH, BUF)                                             \
  {                                                                           \
    char* wbase = (char*)(BUF) + kb + ((CH) >> 1) * 512;                      \
    _Pragma("unroll")                                                         \
    for (int qi = 0; qi < 2; ++qi) {                                          \
      int pa = ((CH)&1) * 32 + u2 + qi * 16;                                  \
      u32 w0 = (u32)f2bf(GA[CH][qi].x) | ((u32)f2bf(GB[CH][qi].x) << 16);     \
      u32 w1 = (u32)f2bf(GA[CH][qi].y) | ((u32)f2bf(GB[CH][qi].y) << 16);     \
      *(u32*)(wbase + pa * ROWB) = w0;                                        \
      *(u32*)(wbase + (pa + 1) * ROWB) = w1;                                  \
    }                                                                         \
  }

// 32 b128 reads + 32 MFMA: all of input half H (k range H*256..+256).
#define COMPUTE_H(H, BUF)                                                     \
  {                                                                           \
    _Pragma("unroll")                                                         \
    for (int ks8 = 0; ks8 < 8; ++ks8) {                                       \
      const int ks = (H) * 8 + ks8;                                           \
      const char* rbase = (const char*)(BUF) + ks * 64 + kg16 + r15 * ROWB;   \
      _Pragma("unroll")                                                       \
      for (int nf = 0; nf < 4; ++nf) {                                        \
        bf16x8 bfr = *(const bf16x8*)(rbase + nf * 16 * ROWB);                \
        acc[nf] = __builtin_amdgcn_mfma_f32_16x16x32_bf16(Af[ks], bfr,        \
                                                          acc[nf], 0, 0, 0); \
      }                                                                       \
    }                                                                         \
  }

// One tile: issue t+2 into bank BI, compute cur, write t+1 from bank BW.
#define BODY(T, CUR, NXT, GAI, GBI, GAW, GBW)                                 \
  {                                                                           \
    f32x4 acc[4];                                                             \
    acc[0] = acc[1] = acc[2] = acc[3] = (f32x4){0.f, 0.f, 0.f, 0.f};          \
    if ((T) + 2 < NT) ISSUE_T(GAI, GBI, (tile0 + (T) + 2) * 64)               \
    COMPUTE_H(0, CUR)                                                         \
    if ((T) + 1 < NT) { WRITE_CH(GAW, GBW, 0, NXT) WRITE_CH(GAW, GBW, 1, NXT) } \
    COMPUTE_H(1, CUR)                                                         \
    if ((T) + 1 < NT) { WRITE_CH(GAW, GBW, 2, NXT) WRITE_CH(GAW, GBW, 3, NXT) } \
    _Pragma("unroll")                                                         \
    for (int nf = 0; nf < 4; ++nf) {                                          \
      pool0 += fmaxf(acc[nf][0] * sc4.x + sh4.x, 0.f);                        \
      pool1 += fmaxf(acc[nf][1] * sc4.y + sh4.y, 0.f);                        \
      pool2 += fmaxf(acc[nf][2] * sc4.z + sh4.z, 0.f);                        \
      pool3 += fmaxf(acc[nf][3] * sc4.w + sh4.w, 0.f);                        \
    }                                                                         \
    BARRIER_LGKM();                                                           \
  }

  // ---- prologue: tiles 0,1 into banks; bank0 -> buf0 ----
  ISSUE_T(gA0, gB0, tile0 * 64)
  ISSUE_T(gA1, gB1, (tile0 + 1) * 64)
  WRITE_CH(gA0, gB0, 0, Bl[0]) WRITE_CH(gA0, gB0, 1, Bl[0])
  WRITE_CH(gA0, gB0, 2, Bl[0]) WRITE_CH(gA0, gB0, 3, Bl[0])
  BARRIER_LGKM();

  for (int tt = 0; tt < NT; tt += 2) {
    BODY(tt,     Bl[0], Bl[1], gA0, gB0, gA1, gB1)
    BODY(tt + 1, Bl[1], Bl[0], gA1, gB1, gA0, gB0)
  }

  // reduce over the 16 positions (r15 lanes)
#pragma unroll
  for (int m = 1; m < 16; m <<= 1) {
    pool0 += __shfl_xor(pool0, m);
    pool1 += __shfl_xor(pool1, m);
    pool2 += __shfl_xor(pool2, m);
    pool3 += __shfl_xor(pool3, m);
  }
  if (r15 == 0) {
    float* dst = pool_part + (size_t)blk * 256 + chbase;
    dst[0] = pool0; dst[1] = pool1; dst[2] = pool2; dst[3] = pool3;
  }
}

// -------- kernel 2: tiny MLPs -> per-(b,c) 3x3 kernels + attn coefs --------
// grid 80 = 8 batches x 10 jobs (j=0..8: tap j of all 256 channels; j=9: coef)
__global__ __launch_bounds__(256) void k2_small(
    const float* __restrict__ pool_part,
    const float* __restrict__ w_cg1, const float* __restrict__ w_cg2,
    const float* __restrict__ w_ag1, const float* __restrict__ w_ag2,
    float* __restrict__ cw, float* __restrict__ coef)
{
  __shared__ float pl[256];
  __shared__ float hl[64];
  const int bi = blockIdx.x;
  const int b = bi / 10, j = bi % 10;
  const int t = threadIdx.x;
  float s = 0.f;
  const float* base = pool_part + (size_t)b * 32 * 256 + t;
  for (int blk = 0; blk < 32; ++blk) s += base[blk * 256];   // fixed order
  pl[t] = s * (1.0f / 16384.0f);
  __syncthreads();
  if (j < 9) {
    if (t < 64) {
      float h = 0.f;
      for (int i = 0; i < 256; ++i) h += pl[i] * w_cg1[t * 256 + i];
      hl[t] = fmaxf(h, 0.f);
    }
    __syncthreads();
    const int o = t * 9 + j;                 // row of w_cg2 = c*9 + tap
    float acc = 0.f;
    for (int jj = 0; jj < 64; ++jj) acc += hl[jj] * w_cg2[o * 64 + jj];
    cw[b * 2304 + o] = acc;
  } else {
    if (t < 64) {
      float a = 0.f;
      for (int i = 0; i < 256; ++i) a += pl[i] * w_ag1[t * 256 + i];
      hl[t] = fmaxf(a, 0.f);
    }
    __syncthreads();
    if (t < 2) {
      float acc = 0.f;
      for (int jj = 0; jj < 64; ++jj) acc += hl[jj] * w_ag2[t * 64 + jj];
      coef[b * 2 + t] = 0.25f / (1.0f + expf(-acc));   // 0.25 = L_S * L_C
    }
  }
}

// -------- kernel 3: depthwise 3x3 (same kernel on x1 & x2) + combine --------
__global__ __launch_bounds__(256) void k3_dynconv(
    const float* __restrict__ x1, const float* __restrict__ x2,
    const float* __restrict__ cw, const float* __restrict__ coef,
    float* __restrict__ out)
{
  __shared__ float t1[34 * 128];
  __shared__ float t2[34 * 128];
  const int tid   = threadIdx.x;
  const int blk   = blockIdx.x;
  const int strip = blk & 3;
  const int c     = (blk >> 2) & 255;
  const int b     = blk >> 10;
  const int h0    = strip * 32;

  const size_t plane = ((size_t)b * C_ + c) * HW_;
  const float* p1 = x1 + plane;
  const float* p2 = x2 + plane;

  float tp[9];
#pragma unroll
  for (int e = 0; e < 9; ++e) tp[e] = cw[(b * C_ + c) * 9 + e];
  const float c1 = coef[b * 2 + 0];
  const float c2 = coef[b * 2 + 1];

  for (int f = tid; f < 1088; f += 256) {
    int row = f >> 5;
    int c4  = (f & 31) << 2;
    int gh  = h0 - 1 + row;
    float4 v1 = make_float4(0.f, 0.f, 0.f, 0.f), v2 = v1;
    if (gh >= 0 && gh < 128) {
      v1 = *(const float4*)&p1[gh * 128 + c4];
      v2 = *(const float4*)&p2[gh * 128 + c4];
    }
    *(float4*)&t1[row * 128 + c4] = v1;
    *(float4*)&t2[row * 128 + c4] = v2;
  }
  __syncthreads();

  for (int i = 0; i < 16; ++i) {
    int q   = tid + i * 256;
    int r   = q >> 7;
    int col = q & 127;
    int lr  = r + 1;
    const bool lok = col > 0, rok = col < 127;
    float d1 = 0.f, d2 = 0.f;
#pragma unroll
    for (int dy = 0; dy < 3; ++dy) {
      const float* row1 = &t1[(lr - 1 + dy) * 128];
      const float* row2 = &t2[(lr - 1 + dy) * 128];
      float a1v = lok ? row1[col - 1] : 0.f;
      float b1v = row1[col];
      float e1v = rok ? row1[col + 1] : 0.f;
      float a2v = lok ? row2[col - 1] : 0.f;
      float b2v = row2[col];
      float e2v = rok ? row2[col + 1] : 0.f;
      d1 += a1v * tp[dy * 3 + 0] + b1v * tp[dy * 3 + 1] + e1v * tp[dy * 3 + 2];
      d2 += a2v * tp[dy * 3 + 0] + b2v * tp[dy * 3 + 1] + e2v * tp[dy * 3 + 2];
    }
    float v1 = t1[lr * 128 + col];
    float v2 = t2[lr * 128 + col];
    out[plane + (size_t)(h0 + r) * 128 + col] = 0.5f * (v1 + v2) + c1 * d1 + c2 * d2;
  }
}

extern "C" void kernel_launch(void* const* d_in, const int* in_sizes, int n_in,
                              void* d_out, int out_size, void* d_ws, size_t ws_size,
                              hipStream_t stream) {
  const float* x1    = (const float*)d_in[0];
  const float* x2    = (const float*)d_in[1];
  const float* w_fe  = (const float*)d_in[2];
  const float* gamma = (const float*)d_in[3];
  const float* beta  = (const float*)d_in[4];
  const float* mean  = (const float*)d_in[5];
  const float* var   = (const float*)d_in[6];
  const float* w_cg1 = (const float*)d_in[7];
  const float* w_cg2 = (const float*)d_in[8];
  const float* w_ag1 = (const float*)d_in[9];
  const float* w_ag2 = (const float*)d_in[10];
  float* out = (float*)d_out;

  // workspace layout (~600 KB)
  char* ws = (char*)d_ws;
  unsigned short* Wp = (unsigned short*)(ws);              // [0, 262144)
  float* scale     = (float*)(ws + 262144);                // 1 KB
  float* shift     = (float*)(ws + 263168);                // 1 KB
  float* pool_part = (float*)(ws + 264192);                // 256*256*4 = 256 KB
  float* cw        = (float*)(ws + 526336);                // 73728 B
  float* coef      = (float*)(ws + 600064);                // 64 B

  k0_prep<<<512, 256, 0, stream>>>(w_fe, gamma, beta, mean, var, Wp, scale, shift);
  k1_gemm_pool<<<256, 1024, 0, stream>>>(x1, x2, Wp, scale, shift, pool_part);
  k2_small<<<80, 256, 0, stream>>>(pool_part, w_cg1, w_cg2, w_ag1, w_ag2, cw, coef);
  k3_dynconv<<<8192, 256, 0, stream>>>(x1, x2, cw, coef, out);
}

// Round 7
// 182.328 us; speedup vs baseline: 1.4688x; 1.4688x over previous
//
#include <hip/hip_runtime.h>
#include <stdint.h>
#include <math.h>

#define HW_ 16384   // H*W = 128*128
#define C_  256
#define NT  8       // tiles per block (each tile = 64 positions)

typedef short bf16x8 __attribute__((ext_vector_type(8)));
typedef float f32x4  __attribute__((ext_vector_type(4)));
typedef unsigned int u32;

__device__ __forceinline__ unsigned short f2bf(float f) {
  union { float f; unsigned u; } v; v.f = f;
  unsigned u = v.u;
  u += 0x7fffu + ((u >> 16) & 1u);   // RNE
  return (unsigned short)(u >> 16);
}

// -------- kernel 0: prep (W -> bf16 in MFMA-fragment order, BN consts) ------
// Wp layout: idx = ks*8192 + kg*2048 + mf*128 + r*8 + e  (shorts)
__global__ __launch_bounds__(256) void k0_prep(
    const float* __restrict__ w_fe, const float* __restrict__ gamma,
    const float* __restrict__ beta, const float* __restrict__ mean,
    const float* __restrict__ var, unsigned short* __restrict__ Wp,
    float* __restrict__ scale, float* __restrict__ shift)
{
  int i = blockIdx.x * 256 + threadIdx.x;
  if (i < 131072) {
    int e  = i & 7;
    int r  = (i >> 3) & 15;
    int mf = (i >> 7) & 15;
    int kg = (i >> 11) & 3;
    int ks = i >> 13;
    int row = mf * 16 + r;              // output channel
    int k   = ks * 32 + kg * 8 + e;     // input channel (0..511)
    Wp[i] = f2bf(w_fe[row * 512 + k]);
  }
  if (i < 256) {
    float sc = gamma[i] * rsqrtf(var[i] + 1e-5f);
    scale[i] = sc;
    shift[i] = beta[i] - mean[i] * sc;
  }
}

// ------- kernel 1: persistent-W bf16 MFMA GEMM + BN + ReLU + pool -------
// 16 waves; wave w = m-frag w (channels w*16..+16). A-frags live in regs/AGPRs.
// X tile in LDS stored FRAGMENT-LINEAR: frag (ks,nf) = 1 KB block at
// (ks*4+nf)*1024; lane l reads its b128 at +l*16 -> conflict-free reads.
// Staging writes scatter (b32, ~4-way, cheap). 1-deep prefetch, one
// __syncthreads per tile. Grid: 256 blocks x 1024 thr, 1 block/CU.
__global__ __launch_bounds__(1024, 4) void k1_gemm_pool(
    const float* __restrict__ x1, const float* __restrict__ x2,
    const unsigned short* __restrict__ Wp,
    const float* __restrict__ scale, const float* __restrict__ shift,
    float* __restrict__ pool_part)
{
  __shared__ __align__(16) char Bl[2][65536];   // 2 x 64KB

  const int tid  = threadIdx.x;
  const int wave = tid >> 6;        // = mf (also staging k-coarse)
  const int lane = tid & 63;
  const int r15  = lane & 15;
  const int kg   = lane >> 4;
  const int blk  = blockIdx.x;
  const int b    = blk >> 5;                 // batch
  const int tile0 = (blk & 31) * NT;

  const float* xb1 = x1 + (size_t)b * C_ * HW_;
  const float* xb2 = x2 + (size_t)b * C_ * HW_;

  // staging decomposition: kp = k-pair within a 256-k half, u2 = pos fine
  const int v  = tid & 7;
  const int u2 = ((tid >> 3) & 7) * 2;
  const int kp = wave * 8 + v;               // 0..127 (k rows 2kp, 2kp+1)

  // per-thread LDS write base for element (pos p, k=H*256+2kp+{0,1}):
  //   byte = (H*8 + kp>>4)*4096 + (p>>4)*1024 + (p&15)*16 + ((kp>>2)&3)*256
  //          + (kp&3)*4
  const int WBASE = (kp >> 4) * 4096 + ((kp >> 2) & 3) * 256 + (kp & 3) * 4
                    + u2 * 16;

  // ---- A-frags once for this wave ----
  bf16x8 Af[16];
#pragma unroll
  for (int ks = 0; ks < 16; ++ks)
    Af[ks] = *(const bf16x8*)(Wp + ks * 8192 + kg * 2048 + wave * 128 + r15 * 8);

  const int chbase = wave * 16 + kg * 4;
  const float4 sc4 = *(const float4*)&scale[chbase];
  const float4 sh4 = *(const float4*)&shift[chbase];

  float pool0 = 0.f, pool1 = 0.f, pool2 = 0.f, pool3 = 0.f;

  float2 gRA[4], gRB[4];   // staging bank: 4 pos-groups x rows (2kp, 2kp+1)

// Load half H of tile at base position P0 (8 x float2 = 16 regs).
#define ISSUE_H(H, P0)                                                        \
  {                                                                           \
    const float* s0 = ((H) == 0 ? xb1 : xb2) + (size_t)(kp * 2) * HW_         \
                      + (P0) + u2;                                            \
    _Pragma("unroll")                                                         \
    for (int G = 0; G < 4; ++G) {                                             \
      gRA[G] = *(const float2*)(s0 + G * 16);                                 \
      gRB[G] = *(const float2*)(s0 + G * 16 + HW_);                           \
    }                                                                         \
  }

// Pack rows (2kp,2kp+1) into u32 pairs, write fragment-linear (8 x b32).
#define WRITE_H(H, BUF)                                                       \
  {                                                                           \
    char* wb = (char*)(BUF) + WBASE + (H) * 32768;                            \
    _Pragma("unroll")                                                         \
    for (int G = 0; G < 4; ++G) {                                             \
      u32 w0 = (u32)f2bf(gRA[G].x) | ((u32)f2bf(gRB[G].x) << 16);             \
      u32 w1 = (u32)f2bf(gRA[G].y) | ((u32)f2bf(gRB[G].y) << 16);             \
      *(u32*)(wb + G * 1024) = w0;                                            \
      *(u32*)(wb + G * 1024 + 16) = w1;                                       \
    }                                                                         \
  }

// 32 linear b128 reads + 32 MFMA: input half H (k range H*256..+256).
#define COMPUTE_H(H, BUF)                                                     \
  {                                                                           \
    _Pragma("unroll")                                                         \
    for (int ks8 = 0; ks8 < 8; ++ks8) {                                       \
      const int ks = (H) * 8 + ks8;                                           \
      const char* rbase = (const char*)(BUF) + ks * 4096 + lane * 16;         \
      _Pragma("unroll")                                                       \
      for (int nf = 0; nf < 4; ++nf) {                                        \
        bf16x8 bfr = *(const bf16x8*)(rbase + nf * 1024);                     \
        acc[nf] = __builtin_amdgcn_mfma_f32_16x16x32_bf16(Af[ks], bfr,        \
                                                          acc[nf], 0, 0, 0); \
      }                                                                       \
    }                                                                         \
  }

  // ---- prologue: stage tile0 into buf 0 ----
  ISSUE_H(0, tile0 * 64) WRITE_H(0, Bl[0])
  ISSUE_H(1, tile0 * 64) WRITE_H(1, Bl[0])
  __syncthreads();

  for (int tt = 0; tt < NT; ++tt) {
    f32x4 acc[4];
#pragma unroll
    for (int nf = 0; nf < 4; ++nf) acc[nf] = (f32x4){0.f, 0.f, 0.f, 0.f};

    const int p0n = (tile0 + tt + 1) * 64;
    const bool more = (tt + 1 < NT);
    const char* cb = Bl[tt & 1];
    char* nxt = Bl[(tt + 1) & 1];

    if (more) ISSUE_H(0, p0n)
    COMPUTE_H(0, cb)
    if (more) { WRITE_H(0, nxt) ISSUE_H(1, p0n) }
    COMPUTE_H(1, cb)
    if (more) WRITE_H(1, nxt)

    // pool accumulate: BN + ReLU over this tile's 64 positions
#pragma unroll
    for (int nf = 0; nf < 4; ++nf) {
      pool0 += fmaxf(acc[nf][0] * sc4.x + sh4.x, 0.f);
      pool1 += fmaxf(acc[nf][1] * sc4.y + sh4.y, 0.f);
      pool2 += fmaxf(acc[nf][2] * sc4.z + sh4.z, 0.f);
      pool3 += fmaxf(acc[nf][3] * sc4.w + sh4.w, 0.f);
    }
    __syncthreads();
  }

  // reduce over the 16 positions (r15 lanes)
#pragma unroll
  for (int m = 1; m < 16; m <<= 1) {
    pool0 += __shfl_xor(pool0, m);
    pool1 += __shfl_xor(pool1, m);
    pool2 += __shfl_xor(pool2, m);
    pool3 += __shfl_xor(pool3, m);
  }
  if (r15 == 0) {
    float* dst = pool_part + (size_t)blk * 256 + chbase;
    dst[0] = pool0; dst[1] = pool1; dst[2] = pool2; dst[3] = pool3;
  }
}

// -------- kernel 2: tiny MLPs -> per-(b,c) 3x3 kernels + attn coefs --------
// grid 80 = 8 batches x 10 jobs (j=0..8: tap j of all 256 channels; j=9: coef)
__global__ __launch_bounds__(256) void k2_small(
    const float* __restrict__ pool_part,
    const float* __restrict__ w_cg1, const float* __restrict__ w_cg2,
    const float* __restrict__ w_ag1, const float* __restrict__ w_ag2,
    float* __restrict__ cw, float* __restrict__ coef)
{
  __shared__ float pl[256];
  __shared__ float hl[64];
  const int bi = blockIdx.x;
  const int b = bi / 10, j = bi % 10;
  const int t = threadIdx.x;
  float s = 0.f;
  const float* base = pool_part + (size_t)b * 32 * 256 + t;
  for (int blk = 0; blk < 32; ++blk) s += base[blk * 256];   // fixed order
  pl[t] = s * (1.0f / 16384.0f);
  __syncthreads();
  if (j < 9) {
    if (t < 64) {
      float h = 0.f;
      for (int i = 0; i < 256; ++i) h += pl[i] * w_cg1[t * 256 + i];
      hl[t] = fmaxf(h, 0.f);
    }
    __syncthreads();
    const int o = t * 9 + j;                 // row of w_cg2 = c*9 + tap
    float acc = 0.f;
    for (int jj = 0; jj < 64; ++jj) acc += hl[jj] * w_cg2[o * 64 + jj];
    cw[b * 2304 + o] = acc;
  } else {
    if (t < 64) {
      float a = 0.f;
      for (int i = 0; i < 256; ++i) a += pl[i] * w_ag1[t * 256 + i];
      hl[t] = fmaxf(a, 0.f);
    }
    __syncthreads();
    if (t < 2) {
      float acc = 0.f;
      for (int jj = 0; jj < 64; ++jj) acc += hl[jj] * w_ag2[t * 64 + jj];
      coef[b * 2 + t] = 0.25f / (1.0f + expf(-acc));   // 0.25 = L_S * L_C
    }
  }
}

// -------- kernel 3: depthwise 3x3 (same kernel on x1 & x2) + combine --------
__global__ __launch_bounds__(256) void k3_dynconv(
    const float* __restrict__ x1, const float* __restrict__ x2,
    const float* __restrict__ cw, const float* __restrict__ coef,
    float* __restrict__ out)
{
  __shared__ float t1[34 * 128];
  __shared__ float t2[34 * 128];
  const int tid   = threadIdx.x;
  const int blk   = blockIdx.x;
  const int strip = blk & 3;
  const int c     = (blk >> 2) & 255;
  const int b     = blk >> 10;
  const int h0    = strip * 32;

  const size_t plane = ((size_t)b * C_ + c) * HW_;
  const float* p1 = x1 + plane;
  const float* p2 = x2 + plane;

  float tp[9];
#pragma unroll
  for (int e = 0; e < 9; ++e) tp[e] = cw[(b * C_ + c) * 9 + e];
  const float c1 = coef[b * 2 + 0];
  const float c2 = coef[b * 2 + 1];

  for (int f = tid; f < 1088; f += 256) {
    int row = f >> 5;
    int c4  = (f & 31) << 2;
    int gh  = h0 - 1 + row;
    float4 v1 = make_float4(0.f, 0.f, 0.f, 0.f), v2 = v1;
    if (gh >= 0 && gh < 128) {
      v1 = *(const float4*)&p1[gh * 128 + c4];
      v2 = *(const float4*)&p2[gh * 128 + c4];
    }
    *(float4*)&t1[row * 128 + c4] = v1;
    *(float4*)&t2[row * 128 + c4] = v2;
  }
  __syncthreads();

  for (int i = 0; i < 16; ++i) {
    int q   = tid + i * 256;
    int r   = q >> 7;
    int col = q & 127;
    int lr  = r + 1;
    const bool lok = col > 0, rok = col < 127;
    float d1 = 0.f, d2 = 0.f;
#pragma unroll
    for (int dy = 0; dy < 3; ++dy) {
      const float* row1 = &t1[(lr - 1 + dy) * 128];
      const float* row2 = &t2[(lr - 1 + dy) * 128];
      float a1v = lok ? row1[col - 1] : 0.f;
      float b1v = row1[col];
      float e1v = rok ? row1[col + 1] : 0.f;
      float a2v = lok ? row2[col - 1] : 0.f;
      float b2v = row2[col];
      float e2v = rok ? row2[col + 1] : 0.f;
      d1 += a1v * tp[dy * 3 + 0] + b1v * tp[dy * 3 + 1] + e1v * tp[dy * 3 + 2];
      d2 += a2v * tp[dy * 3 + 0] + b2v * tp[dy * 3 + 1] + e2v * tp[dy * 3 + 2];
    }
    float v1 = t1[lr * 128 + col];
    float v2 = t2[lr * 128 + col];
    out[plane + (size_t)(h0 + r) * 128 + col] = 0.5f * (v1 + v2) + c1 * d1 + c2 * d2;
  }
}

extern "C" void kernel_launch(void* const* d_in, const int* in_sizes, int n_in,
                              void* d_out, int out_size, void* d_ws, size_t ws_size,
                              hipStream_t stream) {
  const float* x1    = (const float*)d_in[0];
  const float* x2    = (const float*)d_in[1];
  const float* w_fe  = (const float*)d_in[2];
  const float* gamma = (const float*)d_in[3];
  const float* beta  = (const float*)d_in[4];
  const float* mean  = (const float*)d_in[5];
  const float* var   = (const float*)d_in[6];
  const float* w_cg1 = (const float*)d_in[7];
  const float* w_cg2 = (const float*)d_in[8];
  const float* w_ag1 = (const float*)d_in[9];
  const float* w_ag2 = (const float*)d_in[10];
  float* out = (float*)d_out;

  // workspace layout (~600 KB)
  char* ws = (char*)d_ws;
  unsigned short* Wp = (unsigned short*)(ws);              // [0, 262144)
  float* scale     = (float*)(ws + 262144);                // 1 KB
  float* shift     = (float*)(ws + 263168);                // 1 KB
  float* pool_part = (float*)(ws + 264192);                // 256*256*4 = 256 KB
  float* cw        = (float*)(ws + 526336);                // 73728 B
  float* coef      = (float*)(ws + 600064);                // 64 B

  k0_prep<<<512, 256, 0, stream>>>(w_fe, gamma, beta, mean, var, Wp, scale, shift);
  k1_gemm_pool<<<256, 1024, 0, stream>>>(x1, x2, Wp, scale, shift, pool_part);
  k2_small<<<80, 256, 0, stream>>>(pool_part, w_cg1, w_cg2, w_ag1, w_ag2, cw, coef);
  k3_dynconv<<<8192, 256, 0, stream>>>(x1, x2, cw, coef, out);
}

// Round 8
// 153.106 us; speedup vs baseline: 1.7491x; 1.1909x over previous
//
#include <hip/hip_runtime.h>
#include <stdint.h>
#include <math.h>

#define HW_ 16384   // H*W = 128*128
#define C_  256
#define NT  8       // tiles per block (each tile = 64 positions)

typedef long i64;
typedef float f32x4 __attribute__((ext_vector_type(4)));
typedef long i64x2 __attribute__((ext_vector_type(2)));
typedef unsigned int u32;

// -------- kernel 0: prep (W -> fp8 e4m3 in MFMA-fragment order, BN consts) --
// Wp byte layout: idx = ((ks*16 + mf)*64 + kg*16 + r15)*8 + e
//   lane (r15, kg) A-frag for (ks, mf) = 8 contiguous fp8 bytes (1 i64).
__global__ __launch_bounds__(256) void k0_prep(
    const float* __restrict__ w_fe, const float* __restrict__ gamma,
    const float* __restrict__ beta, const float* __restrict__ mean,
    const float* __restrict__ var, u32* __restrict__ Wp,
    float* __restrict__ scale, float* __restrict__ shift)
{
  int i = blockIdx.x * 256 + threadIdx.x;
  if (i < 32768) {                     // one u32 = 4 fp8 bytes
    int e0  = (i & 1) * 4;
    int r15 = (i >> 1) & 15;
    int kg  = (i >> 5) & 3;
    int mf  = (i >> 7) & 15;
    int ks  = i >> 11;
    int row = mf * 16 + r15;
    int k   = ks * 32 + kg * 8 + e0;   // 4 consecutive k
    const float* src = w_fe + row * 512 + k;
    u32 w = 0;
    w = __builtin_amdgcn_cvt_pk_fp8_f32(src[0], src[1], w, false);
    w = __builtin_amdgcn_cvt_pk_fp8_f32(src[2], src[3], w, true);
    Wp[i] = w;
  }
  if (i < 256) {
    float sc = gamma[i] * rsqrtf(var[i] + 1e-5f);
    scale[i] = sc;
    shift[i] = beta[i] - mean[i] * sc;
  }
}

// ------- kernel 1: persistent-W fp8 MFMA GEMM + BN + ReLU + pool -------
// 16 waves; wave w = m-frag w (channels w*16..+16). A-frags (fp8, 32 VGPRs)
// live in regs. X tile [64 pos][512 k] fp8 in LDS, FRAG-PAIR-LINEAR:
// pair (ks, nf>>1) = 1 KB block; lane reads b128 = two B-frags -> conflict-
// free. 1-deep prefetch, one __syncthreads per tile. Grid: 256 x 1024.
__global__ __launch_bounds__(1024, 4) void k1_gemm_pool(
    const float* __restrict__ x1, const float* __restrict__ x2,
    const u32* __restrict__ Wp,
    const float* __restrict__ scale, const float* __restrict__ shift,
    float* __restrict__ pool_part)
{
  __shared__ __align__(16) char Bl[2][32768];   // 2 x 32KB

  const int tid  = threadIdx.x;
  const int wave = tid >> 6;        // = mf
  const int lane = tid & 63;
  const int r15  = lane & 15;
  const int kg   = lane >> 4;
  const int blk  = blockIdx.x;
  const int b    = blk >> 5;                 // batch
  const int tile0 = (blk & 31) * NT;

  const float* xb1 = x1 + (size_t)b * C_ * HW_;
  const float* xb2 = x2 + (size_t)b * C_ * HW_;

  // staging decomposition: thread owns k-octet k8 (8 rows) x 2 positions
  const int p2  = tid & 31;          // position pair (pos 2p2, 2p2+1)
  const int k8  = tid >> 5;          // k-octet 0..31 within a 256-k half
  const int ksL = k8 >> 2;           // local ks 0..7
  const int kgs = k8 & 3;            // k-group within ks
  const int nfs = p2 >> 3;           // frag nf of both positions
  const int L0  = ((2 * p2) & 15) + kgs * 16;   // lane slot of pos 2p2
  // write byte base within buffer (add H*8*2048 for half H):
  const int WB0 = (ksL * 2 + (nfs >> 1)) * 1024 + L0 * 16 + (nfs & 1) * 8;

  // ---- A-frags once for this wave (16 x i64 = 32 VGPRs) ----
  i64 Af[16];
#pragma unroll
  for (int ks = 0; ks < 16; ++ks)
    Af[ks] = *(const i64*)((const char*)Wp
             + ((ks * 16 + wave) * 64 + kg * 16 + r15) * 8);

  const int chbase = wave * 16 + kg * 4;
  const float4 sc4 = *(const float4*)&scale[chbase];
  const float4 sh4 = *(const float4*)&shift[chbase];

  float pool0 = 0.f, pool1 = 0.f, pool2 = 0.f, pool3 = 0.f;

  float2 gR[8];   // staging: 8 k-rows x 2 positions

// Load half H of tile at base position P0 (8 x float2, coalesced 256B segs).
#define ISSUE_H(H, P0)                                                        \
  {                                                                           \
    const float* s0 = ((H) == 0 ? xb1 : xb2) + (size_t)(k8 * 8) * HW_         \
                      + (P0) + 2 * p2;                                        \
    _Pragma("unroll")                                                         \
    for (int r = 0; r < 8; ++r) gR[r] = *(const float2*)(s0 + r * HW_);       \
  }

// Convert to fp8, write 2 x b64 (one per position: full k-octet per lane).
#define WRITE_H(H, BUF)                                                       \
  {                                                                           \
    u32 a0 = 0, a1 = 0, b0 = 0, b1 = 0;                                       \
    a0 = __builtin_amdgcn_cvt_pk_fp8_f32(gR[0].x, gR[1].x, a0, false);        \
    a0 = __builtin_amdgcn_cvt_pk_fp8_f32(gR[2].x, gR[3].x, a0, true);         \
    a1 = __builtin_amdgcn_cvt_pk_fp8_f32(gR[4].x, gR[5].x, a1, false);        \
    a1 = __builtin_amdgcn_cvt_pk_fp8_f32(gR[6].x, gR[7].x, a1, true);         \
    b0 = __builtin_amdgcn_cvt_pk_fp8_f32(gR[0].y, gR[1].y, b0, false);        \
    b0 = __builtin_amdgcn_cvt_pk_fp8_f32(gR[2].y, gR[3].y, b0, true);         \
    b1 = __builtin_amdgcn_cvt_pk_fp8_f32(gR[4].y, gR[5].y, b1, false);        \
    b1 = __builtin_amdgcn_cvt_pk_fp8_f32(gR[6].y, gR[7].y, b1, true);         \
    char* wb = (char*)(BUF) + WB0 + (H) * 16384;                              \
    u32* w0 = (u32*)(wb);                                                     \
    w0[0] = a0; w0[1] = a1;                 /* pos 2p2   */                   \
    u32* w1 = (u32*)(wb + 16);                                                \
    w1[0] = b0; w1[1] = b1;                 /* pos 2p2+1 */                   \
  }

// 16 b128 reads (2 frags each) + 32 MFMA: input half H.
#define COMPUTE_H(H, BUF)                                                     \
  {                                                                           \
    _Pragma("unroll")                                                         \
    for (int ks8 = 0; ks8 < 8; ++ks8) {                                       \
      const int ks = (H) * 8 + ks8;                                           \
      const char* rbase = (const char*)(BUF) + ks * 2048 + lane * 16;         \
      _Pragma("unroll")                                                       \
      for (int np = 0; np < 2; ++np) {                                        \
        i64x2 bq = *(const i64x2*)(rbase + np * 1024);                        \
        acc[np * 2] = __builtin_amdgcn_mfma_f32_16x16x32_fp8_fp8(             \
            Af[ks], bq.x, acc[np * 2], 0, 0, 0);                              \
        acc[np * 2 + 1] = __builtin_amdgcn_mfma_f32_16x16x32_fp8_fp8(         \
            Af[ks], bq.y, acc[np * 2 + 1], 0, 0, 0);                          \
      }                                                                       \
    }                                                                         \
  }

  // ---- prologue: stage tile0 into buf 0 ----
  ISSUE_H(0, tile0 * 64) WRITE_H(0, Bl[0])
  ISSUE_H(1, tile0 * 64) WRITE_H(1, Bl[0])
  __syncthreads();

  for (int tt = 0; tt < NT; ++tt) {
    f32x4 acc[4];
#pragma unroll
    for (int nf = 0; nf < 4; ++nf) acc[nf] = (f32x4){0.f, 0.f, 0.f, 0.f};

    const int p0n = (tile0 + tt + 1) * 64;
    const bool more = (tt + 1 < NT);
    const char* cb = Bl[tt & 1];
    char* nxt = Bl[(tt + 1) & 1];

    if (more) ISSUE_H(0, p0n)
    COMPUTE_H(0, cb)
    if (more) { WRITE_H(0, nxt) ISSUE_H(1, p0n) }
    COMPUTE_H(1, cb)
    if (more) WRITE_H(1, nxt)

    // pool accumulate: BN + ReLU over this tile's 64 positions
#pragma unroll
    for (int nf = 0; nf < 4; ++nf) {
      pool0 += fmaxf(acc[nf][0] * sc4.x + sh4.x, 0.f);
      pool1 += fmaxf(acc[nf][1] * sc4.y + sh4.y, 0.f);
      pool2 += fmaxf(acc[nf][2] * sc4.z + sh4.z, 0.f);
      pool3 += fmaxf(acc[nf][3] * sc4.w + sh4.w, 0.f);
    }
    __syncthreads();
  }

  // reduce over the 16 positions (r15 lanes)
#pragma unroll
  for (int m = 1; m < 16; m <<= 1) {
    pool0 += __shfl_xor(pool0, m);
    pool1 += __shfl_xor(pool1, m);
    pool2 += __shfl_xor(pool2, m);
    pool3 += __shfl_xor(pool3, m);
  }
  if (r15 == 0) {
    float* dst = pool_part + (size_t)blk * 256 + chbase;
    dst[0] = pool0; dst[1] = pool1; dst[2] = pool2; dst[3] = pool3;
  }
}

// -------- kernel 2: tiny MLPs -> per-(b,c) 3x3 kernels + attn coefs --------
// grid 80 = 8 batches x 10 jobs (j=0..8: tap j of all 256 channels; j=9: coef)
__global__ __launch_bounds__(256) void k2_small(
    const float* __restrict__ pool_part,
    const float* __restrict__ w_cg1, const float* __restrict__ w_cg2,
    const float* __restrict__ w_ag1, const float* __restrict__ w_ag2,
    float* __restrict__ cw, float* __restrict__ coef)
{
  __shared__ float pl[256];
  __shared__ float hl[64];
  const int bi = blockIdx.x;
  const int b = bi / 10, j = bi % 10;
  const int t = threadIdx.x;
  float s = 0.f;
  const float* base = pool_part + (size_t)b * 32 * 256 + t;
  for (int blk = 0; blk < 32; ++blk) s += base[blk * 256];   // fixed order
  pl[t] = s * (1.0f / 16384.0f);
  __syncthreads();
  if (j < 9) {
    if (t < 64) {
      float h = 0.f;
      for (int i = 0; i < 256; ++i) h += pl[i] * w_cg1[t * 256 + i];
      hl[t] = fmaxf(h, 0.f);
    }
    __syncthreads();
    const int o = t * 9 + j;                 // row of w_cg2 = c*9 + tap
    float acc = 0.f;
    for (int jj = 0; jj < 64; ++jj) acc += hl[jj] * w_cg2[o * 64 + jj];
    cw[b * 2304 + o] = acc;
  } else {
    if (t < 64) {
      float a = 0.f;
      for (int i = 0; i < 256; ++i) a += pl[i] * w_ag1[t * 256 + i];
      hl[t] = fmaxf(a, 0.f);
    }
    __syncthreads();
    if (t < 2) {
      float acc = 0.f;
      for (int jj = 0; jj < 64; ++jj) acc += hl[jj] * w_ag2[t * 64 + jj];
      coef[b * 2 + t] = 0.25f / (1.0f + expf(-acc));   // 0.25 = L_S * L_C
    }
  }
}

// -------- kernel 3: depthwise 3x3 (same kernel on x1 & x2) + combine --------
__global__ __launch_bounds__(256) void k3_dynconv(
    const float* __restrict__ x1, const float* __restrict__ x2,
    const float* __restrict__ cw, const float* __restrict__ coef,
    float* __restrict__ out)
{
  __shared__ float t1[34 * 128];
  __shared__ float t2[34 * 128];
  const int tid   = threadIdx.x;
  const int blk   = blockIdx.x;
  const int strip = blk & 3;
  const int c     = (blk >> 2) & 255;
  const int b     = blk >> 10;
  const int h0    = strip * 32;

  const size_t plane = ((size_t)b * C_ + c) * HW_;
  const float* p1 = x1 + plane;
  const float* p2 = x2 + plane;

  float tp[9];
#pragma unroll
  for (int e = 0; e < 9; ++e) tp[e] = cw[(b * C_ + c) * 9 + e];
  const float c1 = coef[b * 2 + 0];
  const float c2 = coef[b * 2 + 1];

  for (int f = tid; f < 1088; f += 256) {
    int row = f >> 5;
    int c4  = (f & 31) << 2;
    int gh  = h0 - 1 + row;
    float4 v1 = make_float4(0.f, 0.f, 0.f, 0.f), v2 = v1;
    if (gh >= 0 && gh < 128) {
      v1 = *(const float4*)&p1[gh * 128 + c4];
      v2 = *(const float4*)&p2[gh * 128 + c4];
    }
    *(float4*)&t1[row * 128 + c4] = v1;
    *(float4*)&t2[row * 128 + c4] = v2;
  }
  __syncthreads();

  for (int i = 0; i < 16; ++i) {
    int q   = tid + i * 256;
    int r   = q >> 7;
    int col = q & 127;
    int lr  = r + 1;
    const bool lok = col > 0, rok = col < 127;
    float d1 = 0.f, d2 = 0.f;
#pragma unroll
    for (int dy = 0; dy < 3; ++dy) {
      const float* row1 = &t1[(lr - 1 + dy) * 128];
      const float* row2 = &t2[(lr - 1 + dy) * 128];
      float a1v = lok ? row1[col - 1] : 0.f;
      float b1v = row1[col];
      float e1v = rok ? row1[col + 1] : 0.f;
      float a2v = lok ? row2[col - 1] : 0.f;
      float b2v = row2[col];
      float e2v = rok ? row2[col + 1] : 0.f;
      d1 += a1v * tp[dy * 3 + 0] + b1v * tp[dy * 3 + 1] + e1v * tp[dy * 3 + 2];
      d2 += a2v * tp[dy * 3 + 0] + b2v * tp[dy * 3 + 1] + e2v * tp[dy * 3 + 2];
    }
    float v1 = t1[lr * 128 + col];
    float v2 = t2[lr * 128 + col];
    out[plane + (size_t)(h0 + r) * 128 + col] = 0.5f * (v1 + v2) + c1 * d1 + c2 * d2;
  }
}

extern "C" void kernel_launch(void* const* d_in, const int* in_sizes, int n_in,
                              void* d_out, int out_size, void* d_ws, size_t ws_size,
                              hipStream_t stream) {
  const float* x1    = (const float*)d_in[0];
  const float* x2    = (const float*)d_in[1];
  const float* w_fe  = (const float*)d_in[2];
  const float* gamma = (const float*)d_in[3];
  const float* beta  = (const float*)d_in[4];
  const float* mean  = (const float*)d_in[5];
  const float* var   = (const float*)d_in[6];
  const float* w_cg1 = (const float*)d_in[7];
  const float* w_cg2 = (const float*)d_in[8];
  const float* w_ag1 = (const float*)d_in[9];
  const float* w_ag2 = (const float*)d_in[10];
  float* out = (float*)d_out;

  // workspace layout (~470 KB)
  char* ws = (char*)d_ws;
  u32* Wp          = (u32*)(ws);                           // [0, 131072)
  float* scale     = (float*)(ws + 131072);                // 1 KB
  float* shift     = (float*)(ws + 132096);                // 1 KB
  float* pool_part = (float*)(ws + 133120);                // 256*256*4 = 256 KB
  float* cw        = (float*)(ws + 395264);                // 73728 B
  float* coef      = (float*)(ws + 468992);                // 64 B

  k0_prep<<<128, 256, 0, stream>>>(w_fe, gamma, beta, mean, var, Wp, scale, shift);
  k1_gemm_pool<<<256, 1024, 0, stream>>>(x1, x2, Wp, scale, shift, pool_part);
  k2_small<<<80, 256, 0, stream>>>(pool_part, w_cg1, w_cg2, w_ag1, w_ag2, cw, coef);
  k3_dynconv<<<8192, 256, 0, stream>>>(x1, x2, cw, coef, out);
}

// Round 9
// 152.772 us; speedup vs baseline: 1.7530x; 1.0022x over previous
//
#include <hip/hip_runtime.h>
#include <stdint.h>
#include <math.h>

#define HW_ 16384   // H*W = 128*128
#define C_  256
#define NT  8       // tiles per block (each tile = 64 positions)

typedef long i64;
typedef float f32x4 __attribute__((ext_vector_type(4)));
typedef long i64x2 __attribute__((ext_vector_type(2)));
typedef unsigned int u32;

// barrier WITHOUT vmcnt drain: orders LDS only; prefetch loads stay in flight
#define BARRIER_LGKM() asm volatile("s_waitcnt lgkmcnt(0)\n\ts_barrier" ::: "memory")

// -------- kernel 0: prep (W -> fp8 e4m3 in MFMA-fragment order, BN consts) --
// Wp byte layout: idx = ((ks*16 + mf)*64 + kg*16 + r15)*8 + e
__global__ __launch_bounds__(256) void k0_prep(
    const float* __restrict__ w_fe, const float* __restrict__ gamma,
    const float* __restrict__ beta, const float* __restrict__ mean,
    const float* __restrict__ var, u32* __restrict__ Wp,
    float* __restrict__ scale, float* __restrict__ shift)
{
  int i = blockIdx.x * 256 + threadIdx.x;
  if (i < 32768) {                     // one u32 = 4 fp8 bytes
    int e0  = (i & 1) * 4;
    int r15 = (i >> 1) & 15;
    int kg  = (i >> 5) & 3;
    int mf  = (i >> 7) & 15;
    int ks  = i >> 11;
    int row = mf * 16 + r15;
    int k   = ks * 32 + kg * 8 + e0;   // 4 consecutive k
    const float* src = w_fe + row * 512 + k;
    u32 w = 0;
    w = __builtin_amdgcn_cvt_pk_fp8_f32(src[0], src[1], w, false);
    w = __builtin_amdgcn_cvt_pk_fp8_f32(src[2], src[3], w, true);
    Wp[i] = w;
  }
  if (i < 256) {
    float sc = gamma[i] * rsqrtf(var[i] + 1e-5f);
    scale[i] = sc;
    shift[i] = beta[i] - mean[i] * sc;
  }
}

// ------- kernel 1: persistent-W fp8 MFMA GEMM + BN + ReLU + pool -------
// 16 waves; wave w = m-frag w. A-frags (fp8, 32 VGPRs) in regs. X tile fp8 in
// LDS, frag-pair-linear (conflict-free b128 reads), double-buffered.
// 2-deep half-tile register prefetch: banks gA/gB always hold the NEXT tile
// in flight; counted vmcnt at WRITE; lgkm-only barrier (loads cross barriers).
__global__ __launch_bounds__(1024, 4) void k1_gemm_pool(
    const float* __restrict__ x1, const float* __restrict__ x2,
    const u32* __restrict__ Wp,
    const float* __restrict__ scale, const float* __restrict__ shift,
    float* __restrict__ pool_part)
{
  __shared__ __align__(16) char Bl[2][32768];   // 2 x 32KB

  const int tid  = threadIdx.x;
  const int wave = tid >> 6;        // = mf
  const int lane = tid & 63;
  const int r15  = lane & 15;
  const int kg   = lane >> 4;
  const int blk  = blockIdx.x;
  const int b    = blk >> 5;                 // batch
  const int tile0 = (blk & 31) * NT;

  const float* xb1 = x1 + (size_t)b * C_ * HW_;
  const float* xb2 = x2 + (size_t)b * C_ * HW_;

  // staging decomposition: thread owns k-octet k8 (8 rows) x 2 positions
  const int p2  = tid & 31;          // position pair (pos 2p2, 2p2+1)
  const int k8  = tid >> 5;          // k-octet 0..31 within a 256-k half
  const int ksL = k8 >> 2;           // local ks 0..7
  const int kgs = k8 & 3;            // k-group within ks
  const int nfs = p2 >> 3;           // frag nf of both positions
  const int L0  = ((2 * p2) & 15) + kgs * 16;   // lane slot of pos 2p2
  const int WB0 = (ksL * 2 + (nfs >> 1)) * 1024 + L0 * 16 + (nfs & 1) * 8;

  // ---- A-frags once for this wave (16 x i64 = 32 VGPRs) ----
  i64 Af[16];
#pragma unroll
  for (int ks = 0; ks < 16; ++ks)
    Af[ks] = *(const i64*)((const char*)Wp
             + ((ks * 16 + wave) * 64 + kg * 16 + r15) * 8);

  const int chbase = wave * 16 + kg * 4;
  const float4 sc4 = *(const float4*)&scale[chbase];
  const float4 sh4 = *(const float4*)&shift[chbase];

  float pool0 = 0.f, pool1 = 0.f, pool2 = 0.f, pool3 = 0.f;

  float2 gA[8], gB[8];   // two half-tile prefetch banks (16 regs each)

// Load half H of tile at base position P0 into bank G (8 x float2).
#define ISSUE_HB(G, H, P0)                                                    \
  {                                                                           \
    const float* s0 = ((H) == 0 ? xb1 : xb2) + (size_t)(k8 * 8) * HW_         \
                      + (P0) + 2 * p2;                                        \
    _Pragma("unroll")                                                         \
    for (int r = 0; r < 8; ++r) G[r] = *(const float2*)(s0 + r * HW_);        \
  }

// Convert bank G to fp8, write 2 x b64 (one per position).
#define WRITE_HB(G, H, BUF)                                                   \
  {                                                                           \
    u32 a0 = 0, a1 = 0, b0 = 0, b1 = 0;                                       \
    a0 = __builtin_amdgcn_cvt_pk_fp8_f32(G[0].x, G[1].x, a0, false);          \
    a0 = __builtin_amdgcn_cvt_pk_fp8_f32(G[2].x, G[3].x, a0, true);           \
    a1 = __builtin_amdgcn_cvt_pk_fp8_f32(G[4].x, G[5].x, a1, false);          \
    a1 = __builtin_amdgcn_cvt_pk_fp8_f32(G[6].x, G[7].x, a1, true);           \
    b0 = __builtin_amdgcn_cvt_pk_fp8_f32(G[0].y, G[1].y, b0, false);          \
    b0 = __builtin_amdgcn_cvt_pk_fp8_f32(G[2].y, G[3].y, b0, true);           \
    b1 = __builtin_amdgcn_cvt_pk_fp8_f32(G[4].y, G[5].y, b1, false);          \
    b1 = __builtin_amdgcn_cvt_pk_fp8_f32(G[6].y, G[7].y, b1, true);           \
    char* wb = (char*)(BUF) + WB0 + (H) * 16384;                              \
    u32* w0 = (u32*)(wb);                                                     \
    w0[0] = a0; w0[1] = a1;                 /* pos 2p2   */                   \
    u32* w1 = (u32*)(wb + 16);                                                \
    w1[0] = b0; w1[1] = b1;                 /* pos 2p2+1 */                   \
  }

// 16 b128 reads (2 frags each) + 32 MFMA: input half H.
#define COMPUTE_H(H, BUF)                                                     \
  {                                                                           \
    _Pragma("unroll")                                                         \
    for (int ks8 = 0; ks8 < 8; ++ks8) {                                       \
      const int ks = (H) * 8 + ks8;                                           \
      const char* rbase = (const char*)(BUF) + ks * 2048 + lane * 16;         \
      _Pragma("unroll")                                                       \
      for (int np = 0; np < 2; ++np) {                                        \
        i64x2 bq = *(const i64x2*)(rbase + np * 1024);                        \
        acc[np * 2] = __builtin_amdgcn_mfma_f32_16x16x32_fp8_fp8(             \
            Af[ks], bq.x, acc[np * 2], 0, 0, 0);                              \
        acc[np * 2 + 1] = __builtin_amdgcn_mfma_f32_16x16x32_fp8_fp8(         \
            Af[ks], bq.y, acc[np * 2 + 1], 0, 0, 0);                          \
      }                                                                       \
    }                                                                         \
  }

  // ---- prologue: tile0 loaded+written to buf0; tile1 left IN FLIGHT ----
  ISSUE_HB(gA, 0, tile0 * 64)
  ISSUE_HB(gB, 1, tile0 * 64)
  WRITE_HB(gA, 0, Bl[0])
  WRITE_HB(gB, 1, Bl[0])
  ISSUE_HB(gA, 0, (tile0 + 1) * 64)
  ISSUE_HB(gB, 1, (tile0 + 1) * 64)
  __syncthreads();

  for (int tt = 0; tt < NT; ++tt) {
    f32x4 acc[4];
#pragma unroll
    for (int nf = 0; nf < 4; ++nf) acc[nf] = (f32x4){0.f, 0.f, 0.f, 0.f};

    const int p0i = (tile0 + tt + 2) * 64;
    const bool wri = (tt + 1 < NT);
    const bool iss = (tt + 2 < NT);
    const char* cb = Bl[tt & 1];
    char* nxt = Bl[(tt + 1) & 1];

    COMPUTE_H(0, cb)
    if (wri) WRITE_HB(gA, 0, nxt)      // vmcnt counted: gB still outstanding
    if (iss) ISSUE_HB(gA, 0, p0i)
    COMPUTE_H(1, cb)
    if (wri) WRITE_HB(gB, 1, nxt)      // vmcnt counted: gA(t+2) outstanding
    if (iss) ISSUE_HB(gB, 1, p0i)

    // pool accumulate: BN + ReLU over this tile's 64 positions
#pragma unroll
    for (int nf = 0; nf < 4; ++nf) {
      pool0 += fmaxf(acc[nf][0] * sc4.x + sh4.x, 0.f);
      pool1 += fmaxf(acc[nf][1] * sc4.y + sh4.y, 0.f);
      pool2 += fmaxf(acc[nf][2] * sc4.z + sh4.z, 0.f);
      pool3 += fmaxf(acc[nf][3] * sc4.w + sh4.w, 0.f);
    }
    BARRIER_LGKM();                    // loads stay in flight across barrier
  }

  // reduce over the 16 positions (r15 lanes)
#pragma unroll
  for (int m = 1; m < 16; m <<= 1) {
    pool0 += __shfl_xor(pool0, m);
    pool1 += __shfl_xor(pool1, m);
    pool2 += __shfl_xor(pool2, m);
    pool3 += __shfl_xor(pool3, m);
  }
  if (r15 == 0) {
    float* dst = pool_part + (size_t)blk * 256 + chbase;
    dst[0] = pool0; dst[1] = pool1; dst[2] = pool2; dst[3] = pool3;
  }
}

// -------- kernel 2: tiny MLPs -> per-(b,c) 3x3 kernels + attn coefs --------
// grid 80 = 8 batches x 10 jobs (j=0..8: tap j of all 256 channels; j=9: coef)
__global__ __launch_bounds__(256) void k2_small(
    const float* __restrict__ pool_part,
    const float* __restrict__ w_cg1, const float* __restrict__ w_cg2,
    const float* __restrict__ w_ag1, const float* __restrict__ w_ag2,
    float* __restrict__ cw, float* __restrict__ coef)
{
  __shared__ float pl[256];
  __shared__ float hl[64];
  const int bi = blockIdx.x;
  const int b = bi / 10, j = bi % 10;
  const int t = threadIdx.x;
  float s = 0.f;
  const float* base = pool_part + (size_t)b * 32 * 256 + t;
  for (int blk = 0; blk < 32; ++blk) s += base[blk * 256];   // fixed order
  pl[t] = s * (1.0f / 16384.0f);
  __syncthreads();
  if (j < 9) {
    if (t < 64) {
      float h = 0.f;
      for (int i = 0; i < 256; ++i) h += pl[i] * w_cg1[t * 256 + i];
      hl[t] = fmaxf(h, 0.f);
    }
    __syncthreads();
    const int o = t * 9 + j;                 // row of w_cg2 = c*9 + tap
    float acc = 0.f;
    for (int jj = 0; jj < 64; ++jj) acc += hl[jj] * w_cg2[o * 64 + jj];
    cw[b * 2304 + o] = acc;
  } else {
    if (t < 64) {
      float a = 0.f;
      for (int i = 0; i < 256; ++i) a += pl[i] * w_ag1[t * 256 + i];
      hl[t] = fmaxf(a, 0.f);
    }
    __syncthreads();
    if (t < 2) {
      float acc = 0.f;
      for (int jj = 0; jj < 64; ++jj) acc += hl[jj] * w_ag2[t * 64 + jj];
      coef[b * 2 + t] = 0.25f / (1.0f + expf(-acc));   // 0.25 = L_S * L_C
    }
  }
}

// -------- kernel 3: depthwise 3x3 (same kernel on x1 & x2) + combine --------
__global__ __launch_bounds__(256) void k3_dynconv(
    const float* __restrict__ x1, const float* __restrict__ x2,
    const float* __restrict__ cw, const float* __restrict__ coef,
    float* __restrict__ out)
{
  __shared__ float t1[34 * 128];
  __shared__ float t2[34 * 128];
  const int tid   = threadIdx.x;
  const int blk   = blockIdx.x;
  const int strip = blk & 3;
  const int c     = (blk >> 2) & 255;
  const int b     = blk >> 10;
  const int h0    = strip * 32;

  const size_t plane = ((size_t)b * C_ + c) * HW_;
  const float* p1 = x1 + plane;
  const float* p2 = x2 + plane;

  float tp[9];
#pragma unroll
  for (int e = 0; e < 9; ++e) tp[e] = cw[(b * C_ + c) * 9 + e];
  const float c1 = coef[b * 2 + 0];
  const float c2 = coef[b * 2 + 1];

  for (int f = tid; f < 1088; f += 256) {
    int row = f >> 5;
    int c4  = (f & 31) << 2;
    int gh  = h0 - 1 + row;
    float4 v1 = make_float4(0.f, 0.f, 0.f, 0.f), v2 = v1;
    if (gh >= 0 && gh < 128) {
      v1 = *(const float4*)&p1[gh * 128 + c4];
      v2 = *(const float4*)&p2[gh * 128 + c4];
    }
    *(float4*)&t1[row * 128 + c4] = v1;
    *(float4*)&t2[row * 128 + c4] = v2;
  }
  __syncthreads();

  for (int i = 0; i < 16; ++i) {
    int q   = tid + i * 256;
    int r   = q >> 7;
    int col = q & 127;
    int lr  = r + 1;
    const bool lok = col > 0, rok = col < 127;
    float d1 = 0.f, d2 = 0.f;
#pragma unroll
    for (int dy = 0; dy < 3; ++dy) {
      const float* row1 = &t1[(lr - 1 + dy) * 128];
      const float* row2 = &t2[(lr - 1 + dy) * 128];
      float a1v = lok ? row1[col - 1] : 0.f;
      float b1v = row1[col];
      float e1v = rok ? row1[col + 1] : 0.f;
      float a2v = lok ? row2[col - 1] : 0.f;
      float b2v = row2[col];
      float e2v = rok ? row2[col + 1] : 0.f;
      d1 += a1v * tp[dy * 3 + 0] + b1v * tp[dy * 3 + 1] + e1v * tp[dy * 3 + 2];
      d2 += a2v * tp[dy * 3 + 0] + b2v * tp[dy * 3 + 1] + e2v * tp[dy * 3 + 2];
    }
    float v1 = t1[lr * 128 + col];
    float v2 = t2[lr * 128 + col];
    out[plane + (size_t)(h0 + r) * 128 + col] = 0.5f * (v1 + v2) + c1 * d1 + c2 * d2;
  }
}

extern "C" void kernel_launch(void* const* d_in, const int* in_sizes, int n_in,
                              void* d_out, int out_size, void* d_ws, size_t ws_size,
                              hipStream_t stream) {
  const float* x1    = (const float*)d_in[0];
  const float* x2    = (const float*)d_in[1];
  const float* w_fe  = (const float*)d_in[2];
  const float* gamma = (const float*)d_in[3];
  const float* beta  = (const float*)d_in[4];
  const float* mean  = (const float*)d_in[5];
  const float* var   = (const float*)d_in[6];
  const float* w_cg1 = (const float*)d_in[7];
  const float* w_cg2 = (const float*)d_in[8];
  const float* w_ag1 = (const float*)d_in[9];
  const float* w_ag2 = (const float*)d_in[10];
  float* out = (float*)d_out;

  // workspace layout (~470 KB)
  char* ws = (char*)d_ws;
  u32* Wp          = (u32*)(ws);                           // [0, 131072)
  float* scale     = (float*)(ws + 131072);                // 1 KB
  float* shift     = (float*)(ws + 132096);                // 1 KB
  float* pool_part = (float*)(ws + 133120);                // 256*256*4 = 256 KB
  float* cw        = (float*)(ws + 395264);                // 73728 B
  float* coef      = (float*)(ws + 468992);                // 64 B

  k0_prep<<<128, 256, 0, stream>>>(w_fe, gamma, beta, mean, var, Wp, scale, shift);
  k1_gemm_pool<<<256, 1024, 0, stream>>>(x1, x2, Wp, scale, shift, pool_part);
  k2_small<<<80, 256, 0, stream>>>(pool_part, w_cg1, w_cg2, w_ag1, w_ag2, cw, coef);
  k3_dynconv<<<8192, 256, 0, stream>>>(x1, x2, cw, coef, out);
}